// Round 11
// baseline (322.556 us; speedup 1.0000x reference)
//
#include <hip/hip_runtime.h>
#include <hip/hip_cooperative_groups.h>
#include <math.h>

namespace cg = cooperative_groups;

#define NH 64
#define NW 64
#define NB 4
#define CHI 256
#define CHO 256
#define XT_B (66 * 66 * 256)   // per-batch xT elements (zero-padded 66x66, ch-inner)
#define SMEM_BYTES 29696       // <= 32768 so 2 blocks/CU passes the coop occupancy check

typedef __attribute__((ext_vector_type(8))) short bf16x8;   // MFMA A/B frag (4 VGPR)
typedef __attribute__((ext_vector_type(4))) float f32x4;    // MFMA C/D frag

static __device__ __forceinline__ unsigned short f2bf(float f) {
    unsigned int u = __float_as_uint(f);
    u += 0x7fffu + ((u >> 16) & 1u);     // RNE
    return (unsigned short)(u >> 16);
}
static __device__ __forceinline__ float bflo(unsigned int p) { return __uint_as_float(p << 16); }
static __device__ __forceinline__ float bfhi(unsigned int p) { return __uint_as_float(p & 0xffff0000u); }
static __device__ __forceinline__ unsigned int pkbf(float a, float b) {
    return (unsigned int)f2bf(a) | ((unsigned int)f2bf(b) << 16);
}

// ws: wB bf16[72][256][32] | wOB bf16[72][32][32] | xT bf16[B][66][66][256]
#define T_WB  589824
#define T_WOB 663552           // + 73728
#define T_END 796672           // + 133120 halo uints

// ===================== shared DCN body (everything after xT/wB/wOB are ready) ==============
static __device__ __forceinline__ void dcn_body(unsigned char* smem,
        const unsigned short* __restrict__ xT, const unsigned short* __restrict__ wOB,
        const unsigned short* __restrict__ wB, const float* __restrict__ b_off,
        const float* __restrict__ bias, const float* __restrict__ gamma,
        const float* __restrict__ beta, const float* __restrict__ rmean,
        const float* __restrict__ rvar, float* __restrict__ out, int id, int tid) {
    int4*   s_po = (int4*)smem;                                 // [288]
    float4* s_cw = (float4*)(smem + 4608);                      // [288]
    unsigned short* sA = (unsigned short*)(smem + 9216);        // [8][32*40] (20480 B)
    float* sOff = (float*)(smem + 9216);                        // [2][32][33] aliases sA
    float (*sOut)[256] = (float(*)[256])smem;                   // [16][256] epilogue alias

    int xcd = id & 7, sl = id >> 3;
    int b = xcd >> 1;
    int h = (xcd & 1) * 32 + (sl & 31);
    int pxbase = (sl >> 5) * 32;

    int lane = tid & 63, q = tid >> 6;
    int ln = lane & 15, lk = lane >> 4;
    int nb = q & 3, kh = q >> 2;

    const unsigned short* xTfull = xT + (size_t)b * XT_B;
    const bf16x8* wOBv = (const bf16x8*)wOB;
    const bf16x8* wBv  = (const bf16x8*)wB;

    // ---- offset-conv prologue: fully-unrolled 3-deep pipelined MFMA chain ----
    {
        const int dpos[9] = {-67, -66, -65, -1, 0, 1, 65, 66, 67};
        int omt = q & 1, ont = (q >> 1) & 1, okq = q >> 2;
        int opx = pxbase + omt * 16 + ln;
        size_t obase = (size_t)((h + 1) * 66 + opx + 1) * 256 + lk * 8;
        f32x4 oacc = {0.f, 0.f, 0.f, 0.f};
        int sbeg = okq * 36;   // multiple of 9 -> tap of (sbeg+u) is u%9 (compile-time)
#define LA(u) (*(const bf16x8*)&xTfull[obase + (size_t)dpos[(u) % 9] * 256 + (okq * 4 + (u) / 9) * 32])
#define LB(u) wOBv[((size_t)(sbeg + (u)) * 32 + ont * 16 + ln) * 4 + lk]
        bf16x8 pa0 = LA(0), pb0 = LB(0);
        bf16x8 pa1 = LA(1), pb1 = LB(1);
        bf16x8 pa2 = LA(2), pb2 = LB(2);
#pragma unroll
        for (int t = 0; t < 12; ++t) {
            oacc = __builtin_amdgcn_mfma_f32_16x16x32_bf16(pa0, pb0, oacc, 0, 0, 0);
            if (t < 11) { pa0 = LA(t * 3 + 3); pb0 = LB(t * 3 + 3); }
            oacc = __builtin_amdgcn_mfma_f32_16x16x32_bf16(pa1, pb1, oacc, 0, 0, 0);
            if (t < 11) { pa1 = LA(t * 3 + 4); pb1 = LB(t * 3 + 4); }
            oacc = __builtin_amdgcn_mfma_f32_16x16x32_bf16(pa2, pb2, oacc, 0, 0, 0);
            if (t < 11) { pa2 = LA(t * 3 + 5); pb2 = LB(t * 3 + 5); }
        }
#undef LA
#undef LB
#pragma unroll
        for (int r = 0; r < 4; ++r)
            sOff[(okq * 32 + omt * 16 + lk * 4 + r) * 33 + ont * 16 + ln] = oacc[r];
    }
    __syncthreads();

    // ---- bilinear metadata from in-LDS offsets; sigmoid here ----
    for (int p = tid; p < 288; p += 512) {
        int k = p >> 5, pwl = p & 31, pw = pxbase + pwl;
        float dy = sOff[pwl * 33 + k]      + sOff[(32 + pwl) * 33 + k]      + b_off[k];
        float dx = sOff[pwl * 33 + k + 9]  + sOff[(32 + pwl) * 33 + k + 9]  + b_off[k + 9];
        float mp = sOff[pwl * 33 + k + 18] + sOff[(32 + pwl) * 33 + k + 18] + b_off[k + 18];
        float mv = 1.f / (1.f + __expf(-mp));
        float py  = (float)h  + (float)(k / 3 - 1) + dy;
        float pxf = (float)pw + (float)(k % 3 - 1) + dx;
        float y0f = floorf(py), x0f = floorf(pxf);
        int y0 = (int)y0f, x0 = (int)x0f;
        float ly = py - y0f, lx = pxf - x0f;
        int y0c = min(max(y0, -1), 64), y1c = min(max(y0 + 1, -1), 64);
        int x0c = min(max(x0, -1), 64), x1c = min(max(x0 + 1, -1), 64);
        int ry0 = (y0c + 1) * 66, ry1 = (y1c + 1) * 66;
        s_po[p] = make_int4(ry0 + x0c + 1, ry0 + x1c + 1, ry1 + x0c + 1, ry1 + x1c + 1);
        s_cw[p] = make_float4((1.f - ly) * (1.f - lx) * mv, (1.f - ly) * lx * mv,
                              ly * (1.f - lx) * mv,         ly * lx * mv);
    }

    // producer role: slice-slot sl4, 8 channels cg8*8.., pixel pxl
    int pxl = tid & 31, cg8 = (tid >> 5) & 3, sl4 = tid >> 7;
    int khp = sl4 >> 1, ip = sl4 & 1;
    const unsigned short* xTb = xTfull + cg8 * 8;

    f32x4 zf = {0.f, 0.f, 0.f, 0.f};
    f32x4 acc[2][4] = {{zf, zf, zf, zf}, {zf, zf, zf, zf}};

    uint4 C00, C01, C10, C11;

#define LOADS(s) do { int s_ = (s); int cc_ = s_ / 9; int kt_ = s_ - cc_ * 9;  \
        int4 o4_ = s_po[kt_ * 32 + pxl];                                       \
        const unsigned short* cb_ = xTb + cc_ * 32;                            \
        C00 = *(const uint4*)(cb_ + (size_t)o4_.x * 256);                      \
        C01 = *(const uint4*)(cb_ + (size_t)o4_.y * 256);                      \
        C10 = *(const uint4*)(cb_ + (size_t)o4_.z * 256);                      \
        C11 = *(const uint4*)(cb_ + (size_t)o4_.w * 256);                      \
    } while (0)

#define WRITEA(s, buf) do { int s_ = (s); int kt_ = s_ - (s_ / 9) * 9;         \
        float4 w_ = s_cw[kt_ * 32 + pxl];                                      \
        uint4 pk_;                                                             \
        pk_.x = pkbf(w_.x*bflo(C00.x)+w_.y*bflo(C01.x)+w_.z*bflo(C10.x)+w_.w*bflo(C11.x), \
                     w_.x*bfhi(C00.x)+w_.y*bfhi(C01.x)+w_.z*bfhi(C10.x)+w_.w*bfhi(C11.x)); \
        pk_.y = pkbf(w_.x*bflo(C00.y)+w_.y*bflo(C01.y)+w_.z*bflo(C10.y)+w_.w*bflo(C11.y), \
                     w_.x*bfhi(C00.y)+w_.y*bfhi(C01.y)+w_.z*bfhi(C10.y)+w_.w*bfhi(C11.y)); \
        pk_.z = pkbf(w_.x*bflo(C00.z)+w_.y*bflo(C01.z)+w_.z*bflo(C10.z)+w_.w*bflo(C11.z), \
                     w_.x*bfhi(C00.z)+w_.y*bfhi(C01.z)+w_.z*bfhi(C10.z)+w_.w*bfhi(C11.z)); \
        pk_.w = pkbf(w_.x*bflo(C00.w)+w_.y*bflo(C01.w)+w_.z*bflo(C10.w)+w_.w*bflo(C11.w), \
                     w_.x*bfhi(C00.w)+w_.y*bfhi(C01.w)+w_.z*bfhi(C10.w)+w_.w*bfhi(C11.w)); \
        *(uint4*)&sA[(buf) * 1280 + pxl * 40 + cg8 * 8] = pk_;                 \
    } while (0)

    __syncthreads();   // metadata ready; sOff dead

    LOADS(khp * 36 + ip);
    WRITEA(khp * 36 + ip, sl4);
    LOADS(khp * 36 + 2 + ip);
    bf16x8 bf[4], nbf[4];
#pragma unroll
    for (int j = 0; j < 4; ++j)
        bf[j] = wBv[((size_t)(kh * 36) * 256 + nb * 64 + j * 16 + ln) * 4 + lk];
    __syncthreads();

    for (int g = 0; g < 18; ++g) {
        if (g + 1 < 18) WRITEA(khp * 36 + 2 * (g + 1) + ip, ((g + 1) & 1) * 4 + sl4);
        if (g + 2 < 18) LOADS(khp * 36 + 2 * (g + 2) + ip);
#pragma unroll
        for (int i = 0; i < 2; ++i) {
            int off = 2 * g + i;
            int buf = (g & 1) * 4 + kh * 2 + i;
            bf16x8 af0 = *(const bf16x8*)&sA[buf * 1280 + ln * 40 + lk * 8];
            bf16x8 af1 = *(const bf16x8*)&sA[buf * 1280 + (16 + ln) * 40 + lk * 8];
            bool more = (off + 1 < 36);
            if (more) {
                int sn = kh * 36 + off + 1;
#pragma unroll
                for (int j = 0; j < 4; ++j)
                    nbf[j] = wBv[((size_t)sn * 256 + nb * 64 + j * 16 + ln) * 4 + lk];
            }
#pragma unroll
            for (int j = 0; j < 4; ++j) {
                acc[0][j] = __builtin_amdgcn_mfma_f32_16x16x32_bf16(af0, bf[j], acc[0][j], 0, 0, 0);
                acc[1][j] = __builtin_amdgcn_mfma_f32_16x16x32_bf16(af1, bf[j], acc[1][j], 0, 0, 0);
            }
            if (more) {
#pragma unroll
                for (int j = 0; j < 4; ++j) bf[j] = nbf[j];
            }
        }
        __syncthreads();
    }
#undef LOADS
#undef WRITEA

    // kh-combine + BN + ReLU epilogue, two 16-row rounds (LDS budget: 16*256*4 = 16 KB)
#pragma unroll
    for (int m = 0; m < 2; ++m) {
        if (kh == 1) {
#pragma unroll
            for (int j = 0; j < 4; ++j) {
                int oc = nb * 64 + j * 16 + ln;
#pragma unroll
                for (int r = 0; r < 4; ++r)
                    sOut[lk * 4 + r][oc] = acc[m][j][r];
            }
        }
        __syncthreads();
        if (kh == 0) {
#pragma unroll
            for (int j = 0; j < 4; ++j) {
                int oc = nb * 64 + j * 16 + ln;
                float inv = gamma[oc] * rsqrtf(rvar[oc] + 1e-5f);
                float sh  = beta[oc] - rmean[oc] * inv + bias[oc] * inv;
                int row = lk * 4;
                float4 rr;
                rr.x = fmaxf((acc[m][j][0] + sOut[row + 0][oc]) * inv + sh, 0.f);
                rr.y = fmaxf((acc[m][j][1] + sOut[row + 1][oc]) * inv + sh, 0.f);
                rr.z = fmaxf((acc[m][j][2] + sOut[row + 2][oc]) * inv + sh, 0.f);
                rr.w = fmaxf((acc[m][j][3] + sOut[row + 3][oc]) * inv + sh, 0.f);
                size_t oi = (((size_t)b * 256 + oc) * 64 + h) * 64 + pxbase + m * 16 + row;
                *(float4*)(out + oi) = rr;
            }
        }
        if (m == 0) __syncthreads();
    }
}

// ===================== cooperative all-in-one =====================
__global__ void __launch_bounds__(512) dcn_all(
        const float* __restrict__ x, const float* __restrict__ w_off,
        const float* __restrict__ weight, const float* __restrict__ b_off,
        const float* __restrict__ bias, const float* __restrict__ gamma,
        const float* __restrict__ beta, const float* __restrict__ rmean,
        const float* __restrict__ rvar,
        unsigned short* __restrict__ wB, unsigned short* __restrict__ wOB,
        unsigned short* __restrict__ xT, float* __restrict__ out) {
    __shared__ __align__(16) unsigned char smem[SMEM_BYTES];
    unsigned short* sT = (unsigned short*)smem;                 // [64][134] = 17152 B

    int id = blockIdx.x;                        // 512 blocks
    int tid = threadIdx.x;

    // ---- phase 0: transpose + weight packs + halo zero ----
    {
        int b_ = id >> 7, rem = id & 127, y = rem >> 1, chalf = rem & 1;
        int c0 = chalf * 128;
#pragma unroll
        for (int rep = 0; rep < 4; ++rep) {
            int idx = rep * 512 + tid;          // 0..2047
            int c = idx >> 4, p4 = (idx & 15) * 4;
            float4 v = *(const float4*)(x + (((size_t)b_ * CHI + c0 + c) * 64 + y) * 64 + p4);
            sT[(p4 + 0) * 134 + c] = f2bf(v.x);
            sT[(p4 + 1) * 134 + c] = f2bf(v.y);
            sT[(p4 + 2) * 134 + c] = f2bf(v.z);
            sT[(p4 + 3) * 134 + c] = f2bf(v.w);
        }
        __syncthreads();
        unsigned int* dst = (unsigned int*)(xT + ((size_t)(b_ * 66 + y + 1) * 66 + 1) * 256)
                          + chalf * 64;
#pragma unroll
        for (int rep = 0; rep < 8; ++rep) {
            int idx = rep * 512 + tid;          // 0..4095
            int px = idx >> 6, cu = idx & 63;
            unsigned int lo = sT[px * 134 + cu * 2];
            unsigned int hi = sT[px * 134 + cu * 2 + 1];
            dst[(size_t)px * 128 + cu] = lo | (hi << 16);
        }
        for (int i = id * 512 + tid; i < T_END; i += 512 * 512) {
            if (i < T_WB) {
                int kin = i & 31, o = (i >> 5) & 255, ks = i >> 13;
                int cc = ks / 9, kt = ks - cc * 9;
                wB[i] = f2bf(weight[((size_t)o * CHI + cc * 32 + kin) * 9 + kt]);
            } else if (i < T_WOB) {
                int idx = i - T_WB;
                int kin = idx & 31, oc = (idx >> 5) & 31, ks = idx >> 10;
                int cc = ks / 9, kt = ks - cc * 9;
                wOB[idx] = (oc < 27) ? f2bf(w_off[((size_t)oc * CHI + cc * 32 + kin) * 9 + kt])
                                     : (unsigned short)0;
            } else {
                int r = i - T_WOB;
                int b2 = r / 33280, rr = r - b2 * 33280;
                unsigned int* xtu = (unsigned int*)xT;
                size_t base = (size_t)b2 * 66 * 66 * 128;
                size_t idx;
                if (rr < 8448)       idx = base + rr;
                else if (rr < 16896) idx = base + (size_t)65 * 66 * 128 + (rr - 8448);
                else {
                    int rc = rr - 16896;
                    int side = rc >> 13;
                    int row = 1 + ((rc & 8191) >> 7);
                    int cu = rc & 127;
                    idx = base + ((size_t)row * 66 + (side ? 65 : 0)) * 128 + cu;
                }
                xtu[idx] = 0;
            }
        }
    }
    __threadfence();
    cg::this_grid().sync();
    __syncthreads();

    dcn_body(smem, xT, wOB, wB, b_off, bias, gamma, beta, rmean, rvar, out, id, tid);
}

// ===================== fallback path (round-9 proven structure) =====================
__global__ __launch_bounds__(256) void prep_all(const float* __restrict__ weight,
                                                const float* __restrict__ w_off,
                                                const float* __restrict__ x,
                                                unsigned short* __restrict__ wB,
                                                unsigned short* __restrict__ wOB,
                                                unsigned short* __restrict__ xT) {
    __shared__ unsigned short sT[64 * 134];
    int bid = blockIdx.x, tid = threadIdx.x;
    if (bid < 2304) {
        int idx = bid * 256 + tid;
        int kin = idx & 31, o = (idx >> 5) & 255, ks = idx >> 13;
        int cc = ks / 9, kt = ks - cc * 9;
        wB[idx] = f2bf(weight[((size_t)o * CHI + cc * 32 + kin) * 9 + kt]);
    } else if (bid < 2592) {
        int idx = (bid - 2304) * 256 + tid;
        int kin = idx & 31, oc = (idx >> 5) & 31, ks = idx >> 10;
        int cc = ks / 9, kt = ks - cc * 9;
        wOB[idx] = (oc < 27) ? f2bf(w_off[((size_t)oc * CHI + cc * 32 + kin) * 9 + kt])
                             : (unsigned short)0;
    } else if (bid < 3104) {
        int bid2 = bid - 2592;
        int b = bid2 >> 7, rem = bid2 & 127;
        int y = rem >> 1, chalf = rem & 1;
        int c0 = chalf * 128;
        for (int rep = 0; rep < 8; ++rep) {
            int idx = rep * 256 + tid;
            int c = idx >> 4, p4 = (idx & 15) * 4;
            float4 v = *(const float4*)(x + (((size_t)b * CHI + c0 + c) * 64 + y) * 64 + p4);
            sT[(p4 + 0) * 134 + c] = f2bf(v.x);
            sT[(p4 + 1) * 134 + c] = f2bf(v.y);
            sT[(p4 + 2) * 134 + c] = f2bf(v.z);
            sT[(p4 + 3) * 134 + c] = f2bf(v.w);
        }
        __syncthreads();
        unsigned int* dst = (unsigned int*)(xT + ((size_t)(b * 66 + y + 1) * 66 + 1) * 256)
                          + chalf * 64;
        for (int rep = 0; rep < 16; ++rep) {
            int idx = rep * 256 + tid;
            int px = idx >> 6, cu = idx & 63;
            unsigned int lo = sT[px * 134 + cu * 2];
            unsigned int hi = sT[px * 134 + cu * 2 + 1];
            dst[(size_t)px * 128 + cu] = lo | (hi << 16);
        }
    } else {
        int flat = (bid - 3104) * 256 + tid;
        int b = flat / 33280, r = flat - b * 33280;
        unsigned int* xtu = (unsigned int*)xT;
        size_t base = (size_t)b * 66 * 66 * 128;
        size_t idx;
        if (r < 8448)       idx = base + r;
        else if (r < 16896) idx = base + (size_t)65 * 66 * 128 + (r - 8448);
        else {
            int rc = r - 16896;
            int side = rc >> 13;
            int row = 1 + ((rc & 8191) >> 7);
            int cu = rc & 127;
            idx = base + ((size_t)row * 66 + (side ? 65 : 0)) * 128 + cu;
        }
        xtu[idx] = 0;
    }
}

__global__ void __launch_bounds__(512) dcn_sa(
        const unsigned short* __restrict__ xT, const unsigned short* __restrict__ wOB,
        const unsigned short* __restrict__ wB, const float* __restrict__ b_off,
        const float* __restrict__ bias, const float* __restrict__ gamma,
        const float* __restrict__ beta, const float* __restrict__ rmean,
        const float* __restrict__ rvar, float* __restrict__ out) {
    __shared__ __align__(16) unsigned char smem[SMEM_BYTES];
    dcn_body(smem, xT, wOB, wB, b_off, bias, gamma, beta, rmean, rvar, out,
             blockIdx.x, threadIdx.x);
}

extern "C" void kernel_launch(void* const* d_in, const int* in_sizes, int n_in,
                              void* d_out, int out_size, void* d_ws, size_t ws_size,
                              hipStream_t stream) {
    const float* x      = (const float*)d_in[0];
    const float* w_off  = (const float*)d_in[1];
    const float* b_off  = (const float*)d_in[2];
    const float* weight = (const float*)d_in[3];
    const float* bias   = (const float*)d_in[4];
    const float* gamma  = (const float*)d_in[5];
    const float* beta   = (const float*)d_in[6];
    const float* rmean  = (const float*)d_in[7];
    const float* rvar   = (const float*)d_in[8];
    float* out = (float*)d_out;

    unsigned short* wB  = (unsigned short*)d_ws;             // 589824 bf16
    unsigned short* wOB = wB + 589824;                       // 73728 bf16
    unsigned short* xT  = wOB + 73728;                       // 4 * 66*66*256 bf16

    void* args[] = {(void*)&x, (void*)&w_off, (void*)&weight, (void*)&b_off,
                    (void*)&bias, (void*)&gamma, (void*)&beta, (void*)&rmean,
                    (void*)&rvar, (void*)&wB, (void*)&wOB, (void*)&xT, (void*)&out};
    hipError_t err = hipLaunchCooperativeKernel((void*)dcn_all, dim3(512), dim3(512),
                                                args, 0, stream);
    if (err != hipSuccess) {
        (void)hipGetLastError();   // clear sticky error, take the proven 2-dispatch path
        hipLaunchKernelGGL(prep_all, dim3(3624), dim3(256), 0, stream,
                           weight, w_off, x, wB, wOB, xT);
        hipLaunchKernelGGL(dcn_sa, dim3(512), dim3(512), 0, stream,
                           xT, wOB, wB, b_off, bias, gamma, beta, rmean, rvar, out);
    }
}

// Round 12
// 177.291 us; speedup vs baseline: 1.8194x; 1.8194x over previous
//
#include <hip/hip_runtime.h>
#include <math.h>

#define NH 64
#define NW 64
#define NB 4
#define CHI 256
#define CHO 256
#define XT_B (66 * 66 * 256)   // per-batch xT elements (zero-padded 66x66, ch-inner)
#define SMEM_BYTES 29696

typedef __attribute__((ext_vector_type(8))) short bf16x8;   // MFMA A/B frag (4 VGPR)
typedef __attribute__((ext_vector_type(4))) float f32x4;    // MFMA C/D frag

static __device__ __forceinline__ unsigned short f2bf(float f) {
    unsigned int u = __float_as_uint(f);
    u += 0x7fffu + ((u >> 16) & 1u);     // RNE
    return (unsigned short)(u >> 16);
}
static __device__ __forceinline__ float bflo(unsigned int p) { return __uint_as_float(p << 16); }
static __device__ __forceinline__ float bfhi(unsigned int p) { return __uint_as_float(p & 0xffff0000u); }
static __device__ __forceinline__ unsigned int pkbf(float a, float b) {
    return (unsigned int)f2bf(a) | ((unsigned int)f2bf(b) << 16);
}

// ws: wB bf16[72][256][32] | wOB bf16[72][32][32] | xT bf16[B][66][66][256]

// ---- prep: 512 uniform blocks; linear coalesced reads, scattered writes ----
__global__ __launch_bounds__(256) void prep_fast(const float* __restrict__ weight,
        const float* __restrict__ w_off, const float* __restrict__ x,
        unsigned short* __restrict__ wB, unsigned short* __restrict__ wOB,
        unsigned short* __restrict__ xT) {
    __shared__ unsigned short sT[64 * 134];
    int bid = blockIdx.x, tid = threadIdx.x;

    // part 1: transpose one (b, y, chalf) slice: x[b][c][y][*] f32 -> xT[b][y+1][*+1][c] bf16
    {
        int b = bid >> 7, rem = bid & 127, y = rem >> 1, chalf = rem & 1;
        int c0 = chalf * 128;
#pragma unroll
        for (int rep = 0; rep < 8; ++rep) {
            int idx = rep * 256 + tid;         // 0..2047
            int c = idx >> 4, p4 = (idx & 15) * 4;
            float4 v = *(const float4*)(x + (((size_t)b * CHI + c0 + c) * 64 + y) * 64 + p4);
            sT[(p4 + 0) * 134 + c] = f2bf(v.x);
            sT[(p4 + 1) * 134 + c] = f2bf(v.y);
            sT[(p4 + 2) * 134 + c] = f2bf(v.z);
            sT[(p4 + 3) * 134 + c] = f2bf(v.w);
        }
        __syncthreads();
        unsigned int* dst = (unsigned int*)(xT + ((size_t)(b * 66 + y + 1) * 66 + 1) * 256)
                          + chalf * 64;
#pragma unroll
        for (int rep = 0; rep < 16; ++rep) {
            int idx = rep * 256 + tid;         // 0..4095
            int px = idx >> 6, cu = idx & 63;
            unsigned int lo = sT[px * 134 + cu * 2];
            unsigned int hi = sT[px * 134 + cu * 2 + 1];
            dst[(size_t)px * 128 + cu] = lo | (hi << 16);
        }
    }

    // part 2: grid-stride packs (linear reads -> scattered 2B writes) + halo zero
    const int W1 = 589824;            // weight elements (linear)
    const int W2 = W1 + 62208;        // + w_off elements (27*2304, linear)
    const int W3 = W2 + 11520;        // + wOB oc-padding zeros (72*5*32)
    const int W4 = W3 + 133120;       // + halo uints (4*33280)
    for (int i = bid * 256 + tid; i < W4; i += 512 * 256) {
        if (i < W1) {
            int o = i / 2304, r = i - o * 2304;
            int c = r / 9, kt = r - c * 9;
            int cc = c >> 5, kin = c & 31;
            wB[((size_t)(cc * 9 + kt) * 256 + o) * 32 + kin] = f2bf(weight[i]);
        } else if (i < W2) {
            int j = i - W1;
            int oc = j / 2304, r = j - oc * 2304;
            int c = r / 9, kt = r - c * 9;
            int cc = c >> 5, kin = c & 31;
            wOB[((size_t)(cc * 9 + kt) * 32 + oc) * 32 + kin] = f2bf(w_off[j]);
        } else if (i < W3) {
            int j = i - W2;                    // ks 72 x oc 5 x kin 32
            int kin = j & 31, rest = j >> 5;
            int ks = rest / 5, oc = 27 + (rest - (rest / 5) * 5);
            wOB[((size_t)ks * 32 + oc) * 32 + kin] = 0;
        } else {
            int r = i - W3;                    // 0..133119
            int b2 = r / 33280, rr = r - b2 * 33280;
            unsigned int* xtu = (unsigned int*)xT;
            size_t base = (size_t)b2 * 66 * 66 * 128;
            size_t idx;
            if (rr < 8448)       idx = base + rr;                                  // y=0
            else if (rr < 16896) idx = base + (size_t)65 * 66 * 128 + (rr - 8448); // y=65
            else {
                int rc = rr - 16896;
                int side = rc >> 13;
                int row = 1 + ((rc & 8191) >> 7);
                int cu = rc & 127;
                idx = base + ((size_t)row * 66 + (side ? 65 : 0)) * 128 + cu;
            }
            xtu[idx] = 0;
        }
    }
}

// ---- fused DCN body (round-11 verified): offset prologue + sampling + GEMM + BN/ReLU ----
__global__ void __launch_bounds__(512) dcn_sa(
        const unsigned short* __restrict__ xT, const unsigned short* __restrict__ wOB,
        const unsigned short* __restrict__ wB, const float* __restrict__ b_off,
        const float* __restrict__ bias, const float* __restrict__ gamma,
        const float* __restrict__ beta, const float* __restrict__ rmean,
        const float* __restrict__ rvar, float* __restrict__ out) {
    __shared__ __align__(16) unsigned char smem[SMEM_BYTES];
    int4*   s_po = (int4*)smem;                                 // [288]
    float4* s_cw = (float4*)(smem + 4608);                      // [288]
    unsigned short* sA = (unsigned short*)(smem + 9216);        // [8][32*40]
    float* sOff = (float*)(smem + 9216);                        // [2][32][33] aliases sA
    float (*sOut)[256] = (float(*)[256])smem;                   // [16][256] epilogue alias

    int id = blockIdx.x;
    int tid = threadIdx.x;
    int xcd = id & 7, sl = id >> 3;
    int b = xcd >> 1;
    int h = (xcd & 1) * 32 + (sl & 31);
    int pxbase = (sl >> 5) * 32;

    int lane = tid & 63, q = tid >> 6;
    int ln = lane & 15, lk = lane >> 4;
    int nb = q & 3, kh = q >> 2;

    const unsigned short* xTfull = xT + (size_t)b * XT_B;
    const bf16x8* wOBv = (const bf16x8*)wOB;
    const bf16x8* wBv  = (const bf16x8*)wB;

    // ---- offset-conv prologue: fully-unrolled 3-deep pipelined MFMA chain ----
    {
        const int dpos[9] = {-67, -66, -65, -1, 0, 1, 65, 66, 67};
        int omt = q & 1, ont = (q >> 1) & 1, okq = q >> 2;
        int opx = pxbase + omt * 16 + ln;
        size_t obase = (size_t)((h + 1) * 66 + opx + 1) * 256 + lk * 8;
        f32x4 oacc = {0.f, 0.f, 0.f, 0.f};
        int sbeg = okq * 36;
#define LA(u) (*(const bf16x8*)&xTfull[obase + (size_t)dpos[(u) % 9] * 256 + (okq * 4 + (u) / 9) * 32])
#define LB(u) wOBv[((size_t)(sbeg + (u)) * 32 + ont * 16 + ln) * 4 + lk]
        bf16x8 pa0 = LA(0), pb0 = LB(0);
        bf16x8 pa1 = LA(1), pb1 = LB(1);
        bf16x8 pa2 = LA(2), pb2 = LB(2);
#pragma unroll
        for (int t = 0; t < 12; ++t) {
            oacc = __builtin_amdgcn_mfma_f32_16x16x32_bf16(pa0, pb0, oacc, 0, 0, 0);
            if (t < 11) { pa0 = LA(t * 3 + 3); pb0 = LB(t * 3 + 3); }
            oacc = __builtin_amdgcn_mfma_f32_16x16x32_bf16(pa1, pb1, oacc, 0, 0, 0);
            if (t < 11) { pa1 = LA(t * 3 + 4); pb1 = LB(t * 3 + 4); }
            oacc = __builtin_amdgcn_mfma_f32_16x16x32_bf16(pa2, pb2, oacc, 0, 0, 0);
            if (t < 11) { pa2 = LA(t * 3 + 5); pb2 = LB(t * 3 + 5); }
        }
#undef LA
#undef LB
#pragma unroll
        for (int r = 0; r < 4; ++r)
            sOff[(okq * 32 + omt * 16 + lk * 4 + r) * 33 + ont * 16 + ln] = oacc[r];
    }
    __syncthreads();

    // ---- bilinear metadata from in-LDS offsets; sigmoid here ----
    for (int p = tid; p < 288; p += 512) {
        int k = p >> 5, pwl = p & 31, pw = pxbase + pwl;
        float dy = sOff[pwl * 33 + k]      + sOff[(32 + pwl) * 33 + k]      + b_off[k];
        float dx = sOff[pwl * 33 + k + 9]  + sOff[(32 + pwl) * 33 + k + 9]  + b_off[k + 9];
        float mp = sOff[pwl * 33 + k + 18] + sOff[(32 + pwl) * 33 + k + 18] + b_off[k + 18];
        float mv = 1.f / (1.f + __expf(-mp));
        float py  = (float)h  + (float)(k / 3 - 1) + dy;
        float pxf = (float)pw + (float)(k % 3 - 1) + dx;
        float y0f = floorf(py), x0f = floorf(pxf);
        int y0 = (int)y0f, x0 = (int)x0f;
        float ly = py - y0f, lx = pxf - x0f;
        int y0c = min(max(y0, -1), 64), y1c = min(max(y0 + 1, -1), 64);
        int x0c = min(max(x0, -1), 64), x1c = min(max(x0 + 1, -1), 64);
        int ry0 = (y0c + 1) * 66, ry1 = (y1c + 1) * 66;
        s_po[p] = make_int4(ry0 + x0c + 1, ry0 + x1c + 1, ry1 + x0c + 1, ry1 + x1c + 1);
        s_cw[p] = make_float4((1.f - ly) * (1.f - lx) * mv, (1.f - ly) * lx * mv,
                              ly * (1.f - lx) * mv,         ly * lx * mv);
    }

    // producer role: slice-slot sl4, 8 channels cg8*8.., pixel pxl
    int pxl = tid & 31, cg8 = (tid >> 5) & 3, sl4 = tid >> 7;
    int khp = sl4 >> 1, ip = sl4 & 1;
    const unsigned short* xTb = xTfull + cg8 * 8;

    f32x4 zf = {0.f, 0.f, 0.f, 0.f};
    f32x4 acc[2][4] = {{zf, zf, zf, zf}, {zf, zf, zf, zf}};

    uint4 C00, C01, C10, C11;

#define LOADS(s) do { int s_ = (s); int cc_ = s_ / 9; int kt_ = s_ - cc_ * 9;  \
        int4 o4_ = s_po[kt_ * 32 + pxl];                                       \
        const unsigned short* cb_ = xTb + cc_ * 32;                            \
        C00 = *(const uint4*)(cb_ + (size_t)o4_.x * 256);                      \
        C01 = *(const uint4*)(cb_ + (size_t)o4_.y * 256);                      \
        C10 = *(const uint4*)(cb_ + (size_t)o4_.z * 256);                      \
        C11 = *(const uint4*)(cb_ + (size_t)o4_.w * 256);                      \
    } while (0)

#define WRITEA(s, buf) do { int s_ = (s); int kt_ = s_ - (s_ / 9) * 9;         \
        float4 w_ = s_cw[kt_ * 32 + pxl];                                      \
        uint4 pk_;                                                             \
        pk_.x = pkbf(w_.x*bflo(C00.x)+w_.y*bflo(C01.x)+w_.z*bflo(C10.x)+w_.w*bflo(C11.x), \
                     w_.x*bfhi(C00.x)+w_.y*bfhi(C01.x)+w_.z*bfhi(C10.x)+w_.w*bfhi(C11.x)); \
        pk_.y = pkbf(w_.x*bflo(C00.y)+w_.y*bflo(C01.y)+w_.z*bflo(C10.y)+w_.w*bflo(C11.y), \
                     w_.x*bfhi(C00.y)+w_.y*bfhi(C01.y)+w_.z*bfhi(C10.y)+w_.w*bfhi(C11.y)); \
        pk_.z = pkbf(w_.x*bflo(C00.z)+w_.y*bflo(C01.z)+w_.z*bflo(C10.z)+w_.w*bflo(C11.z), \
                     w_.x*bfhi(C00.z)+w_.y*bfhi(C01.z)+w_.z*bfhi(C10.z)+w_.w*bfhi(C11.z)); \
        pk_.w = pkbf(w_.x*bflo(C00.w)+w_.y*bflo(C01.w)+w_.z*bflo(C10.w)+w_.w*bflo(C11.w), \
                     w_.x*bfhi(C00.w)+w_.y*bfhi(C01.w)+w_.z*bfhi(C10.w)+w_.w*bfhi(C11.w)); \
        *(uint4*)&sA[(buf) * 1280 + pxl * 40 + cg8 * 8] = pk_;                 \
    } while (0)

    __syncthreads();   // metadata ready; sOff dead

    LOADS(khp * 36 + ip);
    WRITEA(khp * 36 + ip, sl4);
    LOADS(khp * 36 + 2 + ip);
    bf16x8 bf[4], nbf[4];
#pragma unroll
    for (int j = 0; j < 4; ++j)
        bf[j] = wBv[((size_t)(kh * 36) * 256 + nb * 64 + j * 16 + ln) * 4 + lk];
    __syncthreads();

    for (int g = 0; g < 18; ++g) {
        if (g + 1 < 18) WRITEA(khp * 36 + 2 * (g + 1) + ip, ((g + 1) & 1) * 4 + sl4);
        if (g + 2 < 18) LOADS(khp * 36 + 2 * (g + 2) + ip);
#pragma unroll
        for (int i = 0; i < 2; ++i) {
            int off = 2 * g + i;
            int buf = (g & 1) * 4 + kh * 2 + i;
            bf16x8 af0 = *(const bf16x8*)&sA[buf * 1280 + ln * 40 + lk * 8];
            bf16x8 af1 = *(const bf16x8*)&sA[buf * 1280 + (16 + ln) * 40 + lk * 8];
            bool more = (off + 1 < 36);
            if (more) {
                int sn = kh * 36 + off + 1;
#pragma unroll
                for (int j = 0; j < 4; ++j)
                    nbf[j] = wBv[((size_t)sn * 256 + nb * 64 + j * 16 + ln) * 4 + lk];
            }
#pragma unroll
            for (int j = 0; j < 4; ++j) {
                acc[0][j] = __builtin_amdgcn_mfma_f32_16x16x32_bf16(af0, bf[j], acc[0][j], 0, 0, 0);
                acc[1][j] = __builtin_amdgcn_mfma_f32_16x16x32_bf16(af1, bf[j], acc[1][j], 0, 0, 0);
            }
            if (more) {
#pragma unroll
                for (int j = 0; j < 4; ++j) bf[j] = nbf[j];
            }
        }
        __syncthreads();
    }
#undef LOADS
#undef WRITEA

    // kh-combine + BN + ReLU epilogue, two 16-row rounds
#pragma unroll
    for (int m = 0; m < 2; ++m) {
        if (kh == 1) {
#pragma unroll
            for (int j = 0; j < 4; ++j) {
                int oc = nb * 64 + j * 16 + ln;
#pragma unroll
                for (int r = 0; r < 4; ++r)
                    sOut[lk * 4 + r][oc] = acc[m][j][r];
            }
        }
        __syncthreads();
        if (kh == 0) {
#pragma unroll
            for (int j = 0; j < 4; ++j) {
                int oc = nb * 64 + j * 16 + ln;
                float inv = gamma[oc] * rsqrtf(rvar[oc] + 1e-5f);
                float sh  = beta[oc] - rmean[oc] * inv + bias[oc] * inv;
                int row = lk * 4;
                float4 rr;
                rr.x = fmaxf((acc[m][j][0] + sOut[row + 0][oc]) * inv + sh, 0.f);
                rr.y = fmaxf((acc[m][j][1] + sOut[row + 1][oc]) * inv + sh, 0.f);
                rr.z = fmaxf((acc[m][j][2] + sOut[row + 2][oc]) * inv + sh, 0.f);
                rr.w = fmaxf((acc[m][j][3] + sOut[row + 3][oc]) * inv + sh, 0.f);
                size_t oi = (((size_t)b * 256 + oc) * 64 + h) * 64 + pxbase + m * 16 + row;
                *(float4*)(out + oi) = rr;
            }
        }
        if (m == 0) __syncthreads();
    }
}

extern "C" void kernel_launch(void* const* d_in, const int* in_sizes, int n_in,
                              void* d_out, int out_size, void* d_ws, size_t ws_size,
                              hipStream_t stream) {
    const float* x      = (const float*)d_in[0];
    const float* w_off  = (const float*)d_in[1];
    const float* b_off  = (const float*)d_in[2];
    const float* weight = (const float*)d_in[3];
    const float* bias   = (const float*)d_in[4];
    const float* gamma  = (const float*)d_in[5];
    const float* beta   = (const float*)d_in[6];
    const float* rmean  = (const float*)d_in[7];
    const float* rvar   = (const float*)d_in[8];
    float* out = (float*)d_out;

    unsigned short* wB  = (unsigned short*)d_ws;             // 589824 bf16
    unsigned short* wOB = wB + 589824;                       // 73728 bf16
    unsigned short* xT  = wOB + 73728;                       // 4 * 66*66*256 bf16

    hipLaunchKernelGGL(prep_fast, dim3(512), dim3(256), 0, stream,
                       weight, w_off, x, wB, wOB, xT);
    hipLaunchKernelGGL(dcn_sa, dim3(512), dim3(512), 0, stream,
                       xT, wOB, wB, b_off, bias, gamma, beta, rmean, rvar, out);
}